// Round 10
// baseline (872.274 us; speedup 1.0000x reference)
//
#include <hip/hip_runtime.h>
#include <stdint.h>

// =====================================================================
// Host-side RNG (HW-VERIFIED r7) — DO NOT TOUCH.
// =====================================================================
namespace rng42 {
typedef unsigned __int128 u128;

static inline uint32_t hashmix(uint32_t v, uint32_t& hc) {
    v ^= hc;
    hc *= 0x931e8875u;
    v *= hc;
    v ^= v >> 16;
    return v;
}
static inline uint32_t mixf(uint32_t x, uint32_t y) {
    uint32_t r = x * 0xca01f9ddu - y * 0x4973f715u;
    r ^= r >> 16;
    return r;
}

struct PCG64 {
    u128 state, inc;
    bool has32; uint32_t buf32;
    static inline u128 mult() {
        return ((u128)2549297995355413924ULL << 64) | (u128)4865540595714422341ULL;
    }
    inline void step() { state = state * mult() + inc; }
    void seed42() {
        uint32_t pool[4];
        uint32_t hc = 0x43b0d7e5u;
        pool[0] = hashmix(42u, hc);
        for (int i = 1; i < 4; i++) pool[i] = hashmix(0u, hc);
        for (int s = 0; s < 4; s++)
            for (int d = 0; d < 4; d++)
                if (s != d) pool[d] = mixf(pool[d], hashmix(pool[s], hc));
        uint32_t hb = 0x8b51f9ddu;
        uint32_t st32[8];
        for (int i = 0; i < 8; i++) {
            uint32_t dv = pool[i & 3];
            dv ^= hb;
            hb *= 0x58f38dedu;
            dv *= hb;
            dv ^= dv >> 16;
            st32[i] = dv;
        }
        uint64_t w0 = (uint64_t)st32[0] | ((uint64_t)st32[1] << 32);
        uint64_t w1 = (uint64_t)st32[2] | ((uint64_t)st32[3] << 32);
        uint64_t w2 = (uint64_t)st32[4] | ((uint64_t)st32[5] << 32);
        uint64_t w3 = (uint64_t)st32[6] | ((uint64_t)st32[7] << 32);
        u128 initstate = ((u128)w0 << 64) | (u128)w1;
        u128 initseq   = ((u128)w2 << 64) | (u128)w3;
        state = 0;
        inc = (initseq << 1) | 1;
        step();
        state += initstate;
        step();
        has32 = false; buf32 = 0;
    }
    uint64_t next64() {
        step();
        uint64_t lo = (uint64_t)state, hi = (uint64_t)(state >> 64);
        uint64_t x = hi ^ lo;
        unsigned rot = (unsigned)(uint64_t)(state >> 122);
        return (x >> rot) | (x << ((64u - rot) & 63u));
    }
    uint32_t next32() {
        if (has32) { has32 = false; return buf32; }
        uint64_t n = next64();
        has32 = true;
        buf32 = (uint32_t)(n >> 32);
        return (uint32_t)(n & 0xffffffffu);
    }
    uint32_t lemire32(uint32_t rng) {
        const uint32_t rng_excl = rng + 1u;
        uint64_t m = (uint64_t)next32() * (uint64_t)rng_excl;
        uint32_t leftover = (uint32_t)m;
        if (leftover < rng_excl) {
            const uint32_t threshold = (uint32_t)(0xFFFFFFFFu - rng) % rng_excl;
            while (leftover < threshold) {
                m = (uint64_t)next32() * (uint64_t)rng_excl;
                leftover = (uint32_t)m;
            }
        }
        return (uint32_t)(m >> 32);
    }
    uint32_t interval(uint32_t mx) {
        if (mx == 0) return 0;
        uint32_t mask = mx;
        mask |= mask >> 1; mask |= mask >> 2; mask |= mask >> 4;
        mask |= mask >> 8; mask |= mask >> 16;
        uint32_t value;
        while ((value = (next32() & mask)) > mx) {}
        return value;
    }
};
} // namespace rng42

struct OpsArg { int v[50]; };

static void gen_ops(OpsArg& o) {
    rng42::PCG64 g;
    g.seed42();
    for (int k = 0; k < 50; k++) {
        int t = (int)g.lemire32(3);
        if (t == 3) {
            int arr[4] = {0, 1, 2, 3};
            for (int i = 3; i >= 1; i--) {
                int j = (int)g.interval((uint32_t)i);
                if (i != j) { int tmp = arr[i]; arr[i] = arr[j]; arr[j] = tmp; }
            }
            o.v[k] = 3 | (arr[0] << 2) | (arr[1] << 4);
        } else {
            int w = (int)g.lemire32(3);
            o.v[k] = t | (w << 2);
        }
    }
}

static int anchors_mask() {
    rng42::PCG64 g;
    g.seed42();
    uint32_t c[6];
    for (int i = 0; i < 6; i++) c[i] = g.next32();
    int m = 0;
    if (c[1] >= 3324113900u && c[1] <= 3324117900u) m |= 1;
    if (c[3] >= 1884966500u && c[3] <= 1884970500u) m |= 2;
    if (c[5] >= 3687648000u && c[5] <= 3687652000u) m |= 4;
    return m;
}

static float diag_payload(int mask) {
    rng42::PCG64 g;
    g.seed42();
    uint64_t D = 0;
    for (int k = 0; k < 5; k++) {
        uint32_t c = g.next32();
        D = D * 10ull + (uint32_t)(((uint64_t)c * 10ull) >> 32);
    }
    return (float)((double)(2 + mask) * 1e7 + (double)D * 10.0);
}

// =====================================================================
// Quantum gate primitives (verified r7). State idx = q0*8+q1*4+q2*2+q3.
// =====================================================================
template<int MASK>
__device__ inline void g_rx(float c, float s, float* re, float* im) {
#pragma unroll
    for (int i = 0; i < 16; i++)
        if (!(i & MASK)) {
            const int j = i | MASK;
            float r0 = re[i], i0 = im[i], r1 = re[j], i1 = im[j];
            re[i] = c * r0 + s * i1; im[i] = c * i0 - s * r1;
            re[j] = s * i0 + c * r1; im[j] = c * i1 - s * r0;
        }
}
template<int MASK>
__device__ inline void g_ry(float c, float s, float* re, float* im) {
#pragma unroll
    for (int i = 0; i < 16; i++)
        if (!(i & MASK)) {
            const int j = i | MASK;
            float r0 = re[i], i0 = im[i], r1 = re[j], i1 = im[j];
            re[i] = c * r0 - s * r1; im[i] = c * i0 - s * i1;
            re[j] = s * r0 + c * r1; im[j] = s * i0 + c * i1;
        }
}
template<int MASK>
__device__ inline void g_rz(float c, float s, float* re, float* im) {
#pragma unroll
    for (int i = 0; i < 16; i++)
        if (!(i & MASK)) {
            const int j = i | MASK;
            float r0 = re[i], i0 = im[i], r1 = re[j], i1 = im[j];
            re[i] = c * r0 + s * i0; im[i] = c * i0 - s * r0;
            re[j] = c * r1 - s * i1; im[j] = c * i1 + s * r1;
        }
}
template<int CM, int TM>
__device__ inline void g_cnot(float* re, float* im) {
#pragma unroll
    for (int i = 0; i < 16; i++)
        if ((i & CM) && !(i & TM)) {
            const int j = i | TM;
            float tr = re[i]; re[i] = re[j]; re[j] = tr;
            float ti = im[i]; im[i] = im[j]; im[j] = ti;
        }
}

__device__ inline void rot_rt(int ty, int w, float c, float s, float* re, float* im) {
    switch (ty * 4 + w) {
        case 0:  g_rx<8>(c, s, re, im); break;
        case 1:  g_rx<4>(c, s, re, im); break;
        case 2:  g_rx<2>(c, s, re, im); break;
        case 3:  g_rx<1>(c, s, re, im); break;
        case 4:  g_ry<8>(c, s, re, im); break;
        case 5:  g_ry<4>(c, s, re, im); break;
        case 6:  g_ry<2>(c, s, re, im); break;
        case 7:  g_ry<1>(c, s, re, im); break;
        case 8:  g_rz<8>(c, s, re, im); break;
        case 9:  g_rz<4>(c, s, re, im); break;
        case 10: g_rz<2>(c, s, re, im); break;
        case 11: g_rz<1>(c, s, re, im); break;
        default: break;
    }
}
__device__ inline void cnot_rt(int w0, int w1, float* re, float* im) {
    switch (w0 * 4 + w1) {
        case 1:  g_cnot<8, 4>(re, im); break;
        case 2:  g_cnot<8, 2>(re, im); break;
        case 3:  g_cnot<8, 1>(re, im); break;
        case 4:  g_cnot<4, 8>(re, im); break;
        case 6:  g_cnot<4, 2>(re, im); break;
        case 7:  g_cnot<4, 1>(re, im); break;
        case 8:  g_cnot<2, 8>(re, im); break;
        case 9:  g_cnot<2, 4>(re, im); break;
        case 11: g_cnot<2, 1>(re, im); break;
        case 12: g_cnot<1, 8>(re, im); break;
        case 13: g_cnot<1, 4>(re, im); break;
        case 14: g_cnot<1, 2>(re, im); break;
        default: break;
    }
}

__device__ inline float dot4(const float4& w, const float4& p) {
    return w.x * p.x + w.y * p.y + w.z * p.z + w.w * p.w;
}

// =====================================================================
// K1: per-image CNN. Padded LDS (static offsets, no bounds predication):
//  xs:  30x30 zero-padded input
//  c1s: 16x16 sites x 8 ch, channel-last, zero halo -> conv2 imm-offset
//  conv1 weights/bias read from global with uniform idx -> s_load.
// =====================================================================
__global__ __launch_bounds__(256, 4) void k_cnn(
    const float* __restrict__ x,
    const float* __restrict__ c1w, const float* __restrict__ c1b,
    const float* __restrict__ c2w, const float* __restrict__ c2b,
    const float* __restrict__ w1, const float* __restrict__ b1,
    const float* __restrict__ w2, const float* __restrict__ b2,
    const float* __restrict__ w3, const float* __restrict__ b3,
    float* __restrict__ pooled_g, float* __restrict__ mlp_g)
{
    __shared__ __align__(16) float xs[900];        // 30x30 padded
    __shared__ __align__(16) float c1s[256 * 8];   // 16x16 sites x 8ch
    __shared__ __align__(16) float c2s[784];
    __shared__ __align__(16) float wl2[1152];
    __shared__ float h1s[8];

    const int b = blockIdx.x;
    const int t = threadIdx.x;

    // phase a: zero padded buffers
    for (int i = t; i < 900; i += 256) xs[i] = 0.f;
    for (int i = t; i < 2048; i += 256) c1s[i] = 0.f;
    __syncthreads();

    // phase b: interior load + weight permute
    const float* xb = x + b * 784;
    for (int i = t; i < 784; i += 256) {
        int y = i / 28, xcol = i % 28;
        xs[(y + 1) * 30 + (xcol + 1)] = xb[i];
    }
    for (int i = t; i < 1152; i += 256) {
        int oc = i / 72, r = i % 72, ic = r / 9, k9 = r % 9;
        wl2[(oc * 9 + k9) * 8 + ic] = c2w[i];
    }
    __syncthreads();

    // avg-pool 6x6 stride 6 -> pooled[16]
    if (t < 16) {
        int r0 = (t >> 2) * 6, c0 = (t & 3) * 6;
        float s = 0.f;
#pragma unroll
        for (int dy = 0; dy < 6; dy++)
#pragma unroll
            for (int dx = 0; dx < 6; dx++)
                s += xs[(r0 + dy + 1) * 30 + (c0 + dx + 1)];
        pooled_g[b * 16 + t] = s * (1.0f / 36.0f);
    }

    // conv1 + relu + 2x2 maxpool: 196 threads, 8 oc, channel-last out
    if (t < 196) {
        const int py = t / 14, px = t % 14;
        const int pbx = (2 * py) * 30 + 2 * px;  // padded base (y0=2py-1 -> row 2py)
        float patch[16];
#pragma unroll
        for (int i = 0; i < 4; i++)
#pragma unroll
            for (int j = 0; j < 4; j++)
                patch[i * 4 + j] = xs[pbx + i * 30 + j];   // imm offsets
        float m8[8];
#pragma unroll
        for (int oc = 0; oc < 8; oc++) {
            float w[9];
#pragma unroll
            for (int i = 0; i < 9; i++) w[i] = c1w[oc * 9 + i];  // uniform -> s_load
            const float bias = c1b[oc];                           // uniform -> s_load
            float m = 0.f;
#pragma unroll
            for (int dy = 0; dy < 2; dy++)
#pragma unroll
                for (int dx = 0; dx < 2; dx++) {
                    float acc = bias;
#pragma unroll
                    for (int ky = 0; ky < 3; ky++)
#pragma unroll
                        for (int kx = 0; kx < 3; kx++)
                            acc += w[ky * 3 + kx] * patch[(dy + ky) * 4 + (dx + kx)];
                    m = fmaxf(m, acc);
                }
            m8[oc] = m;
        }
        // site = (py+1)*16 + (px+1)
        float4* cv = (float4*)&c1s[((py + 1) * 16 + px + 1) * 8];
        cv[0] = make_float4(m8[0], m8[1], m8[2], m8[3]);
        cv[1] = make_float4(m8[4], m8[5], m8[6], m8[7]);
    }
    __syncthreads();

    // conv2 + relu + 2x2 maxpool: thread = (oc = t&15, pbase = t>>4);
    // 4 pooled outputs p = pbase + 16*pi; clamp p>=49 -> redundant compute
    {
        const int oc = t & 15;
        const int pbase = t >> 4;
        const float bias = c2b[oc];
        float a[4][2][2];
#pragma unroll
        for (int pi = 0; pi < 4; pi++)
#pragma unroll
            for (int dy = 0; dy < 2; dy++)
#pragma unroll
                for (int dx = 0; dx < 2; dx++) a[pi][dy][dx] = bias;

        const float4* wv = (const float4*)wl2;
        const float4* cv = (const float4*)c1s;

#pragma unroll
        for (int h = 0; h < 2; h++) {
            float4 W[9];
#pragma unroll
            for (int k = 0; k < 9; k++) W[k] = wv[(oc * 9 + k) * 2 + h];
#pragma unroll
            for (int pi = 0; pi < 4; pi++) {
                const int p = pbase + 16 * pi;
                const int pc = p < 49 ? p : 48;
                const int py = pc / 7, px = pc % 7;
                const int rowbase = (2 * py) * 16 + 2 * px;  // padded site
#pragma unroll
                for (int i = 0; i < 4; i++) {
                    const int s0 = (rowbase + i * 16) * 2 + h;
                    float4 r0 = cv[s0];
                    float4 r1 = cv[s0 + 2];
                    float4 r2 = cv[s0 + 4];
                    float4 r3 = cv[s0 + 6];
#pragma unroll
                    for (int dy = 0; dy < 2; dy++) {
                        if (dy <= i && i <= dy + 2) {
                            const int ky = i - dy;
                            const float4 wk0 = W[ky * 3 + 0];
                            const float4 wk1 = W[ky * 3 + 1];
                            const float4 wk2 = W[ky * 3 + 2];
                            a[pi][dy][0] += dot4(wk0, r0) + dot4(wk1, r1) + dot4(wk2, r2);
                            a[pi][dy][1] += dot4(wk0, r1) + dot4(wk1, r2) + dot4(wk2, r3);
                        }
                    }
                }
            }
        }
#pragma unroll
        for (int pi = 0; pi < 4; pi++) {
            const int p = pbase + 16 * pi;
            if (p < 49) {
                float m = fmaxf(fmaxf(a[pi][0][0], a[pi][0][1]),
                                fmaxf(a[pi][1][0], a[pi][1][1]));
                c2s[oc * 49 + p] = fmaxf(m, 0.f);
            }
        }
    }
    __syncthreads();

    // MLP layer1: 8 outputs x 32 lanes, f4 vectorized (196 f4 per row)
    {
        const int o = t >> 5, lane = t & 31;
        const float4* c2v = (const float4*)c2s;
        const float4* w1v = (const float4*)(w1 + o * 784);
        float s = 0.f;
#pragma unroll
        for (int j = 0; j < 7; j++) {
            const int idx = lane + j * 32;
            if (idx < 196) {
                float4 cvv = c2v[idx];
                float4 wvv = w1v[idx];
                s += cvv.x * wvv.x + cvv.y * wvv.y + cvv.z * wvv.z + cvv.w * wvv.w;
            }
        }
#pragma unroll
        for (int d = 16; d > 0; d >>= 1) s += __shfl_down(s, d, 32);
        if (lane == 0) h1s[o] = tanhf(s + b1[o]);
    }
    __syncthreads();
    if (t == 0) {
        float h2[4];
#pragma unroll
        for (int o = 0; o < 4; o++) {
            float s = b2[o];
#pragma unroll
            for (int j = 0; j < 8; j++) s += h1s[j] * w2[o * 8 + j];
            h2[o] = tanhf(s);
        }
        float s = b3[0];
#pragma unroll
        for (int j = 0; j < 4; j++) s += h2[j] * w3[j];
        mlp_g[b] = s;
    }
}

// =====================================================================
// K2: quantum block, one thread per batch element; block = 1 wave (64).
// Emits per-block partial sums/sumsq of qout for fused BN stats.
// =====================================================================
__global__ __launch_bounds__(64) void k_quantum(
    const float* __restrict__ pooled_g, const float* __restrict__ rl,
    const float* __restrict__ prx0, const float* __restrict__ pry0,
    const float* __restrict__ prz0, const float* __restrict__ pcrx0,
    float* __restrict__ qout, float* __restrict__ part1, OpsArg ops)
{
    __shared__ float rc[50], rs[50];
    const int t = threadIdx.x;
    if (t < 50) {
        float a = 0.5f * rl[t];
        rc[t] = cosf(a);
        rs[t] = sinf(a);
    }
    __syncthreads();

    const int b = blockIdx.x * 64 + t;
    float re[16], im[16];
#pragma unroll
    for (int i = 0; i < 16; i++) { re[i] = 0.f; im[i] = 0.f; }
    re[0] = 1.f;

    const float4* pv = (const float4*)(pooled_g + b * 16);
    float pb[16];
    {
        float4 p0 = pv[0], p1 = pv[1], p2 = pv[2], p3 = pv[3];
        pb[0] = p0.x; pb[1] = p0.y; pb[2] = p0.z; pb[3] = p0.w;
        pb[4] = p1.x; pb[5] = p1.y; pb[6] = p1.z; pb[7] = p1.w;
        pb[8] = p2.x; pb[9] = p2.y; pb[10] = p2.z; pb[11] = p2.w;
        pb[12] = p3.x; pb[13] = p3.y; pb[14] = p3.z; pb[15] = p3.w;
    }
    {
        float c, s, a;
        a = 0.5f * pb[0];  c = cosf(a); s = sinf(a); g_ry<8>(c, s, re, im);
        a = 0.5f * pb[1];  c = cosf(a); s = sinf(a); g_ry<4>(c, s, re, im);
        a = 0.5f * pb[2];  c = cosf(a); s = sinf(a); g_ry<2>(c, s, re, im);
        a = 0.5f * pb[3];  c = cosf(a); s = sinf(a); g_ry<1>(c, s, re, im);
        a = 0.5f * pb[4];  c = cosf(a); s = sinf(a); g_rz<8>(c, s, re, im);
        a = 0.5f * pb[5];  c = cosf(a); s = sinf(a); g_rz<4>(c, s, re, im);
        a = 0.5f * pb[6];  c = cosf(a); s = sinf(a); g_rz<2>(c, s, re, im);
        a = 0.5f * pb[7];  c = cosf(a); s = sinf(a); g_rz<1>(c, s, re, im);
        a = 0.5f * pb[8];  c = cosf(a); s = sinf(a); g_rx<8>(c, s, re, im);
        a = 0.5f * pb[9];  c = cosf(a); s = sinf(a); g_rx<4>(c, s, re, im);
        a = 0.5f * pb[10]; c = cosf(a); s = sinf(a); g_rx<2>(c, s, re, im);
        a = 0.5f * pb[11]; c = cosf(a); s = sinf(a); g_rx<1>(c, s, re, im);
        a = 0.5f * pb[12]; c = cosf(a); s = sinf(a); g_ry<8>(c, s, re, im);
        a = 0.5f * pb[13]; c = cosf(a); s = sinf(a); g_ry<4>(c, s, re, im);
        a = 0.5f * pb[14]; c = cosf(a); s = sinf(a); g_ry<2>(c, s, re, im);
        a = 0.5f * pb[15]; c = cosf(a); s = sinf(a); g_ry<1>(c, s, re, im);
    }

#pragma unroll 1
    for (int k = 0; k < 50; k++) {
        int v = ops.v[k];
        int ty = v & 3;
        int w0 = (v >> 2) & 3;
        int w1 = (v >> 4) & 3;
        if (ty == 3) cnot_rt(w0, w1, re, im);
        else         rot_rt(ty, w0, rc[k], rs[k], re, im);
    }

    { float a = 0.5f * prx0[0];  g_rx<8>(cosf(a), sinf(a), re, im); }
    { float a = 0.5f * pry0[0];  g_ry<4>(cosf(a), sinf(a), re, im); }
    { float a = 0.5f * prz0[0];  g_rz<1>(cosf(a), sinf(a), re, im); }
    { // crx (control wire0=mask8, target wire2=mask2)
        float a = 0.5f * pcrx0[0];
        float c = cosf(a), s = sinf(a);
#pragma unroll
        for (int i = 0; i < 16; i++)
            if ((i & 8) && !(i & 2)) {
                const int j = i | 2;
                float r0 = re[i], i0 = im[i], r1 = re[j], i1 = im[j];
                re[i] = c * r0 + s * i1; im[i] = c * i0 - s * r1;
                re[j] = s * i0 + c * r1; im[j] = c * i1 - s * r0;
            }
    }
    { // H wire 3
        const float r2 = 0.70710678118654752f;
#pragma unroll
        for (int i = 0; i < 16; i++)
            if (!(i & 1)) {
                const int j = i | 1;
                float r0 = re[i], i0 = im[i], r1 = re[j], i1 = im[j];
                re[i] = (r0 + r1) * r2; im[i] = (i0 + i1) * r2;
                re[j] = (r0 - r1) * r2; im[j] = (i0 - i1) * r2;
            }
    }
    { // SX wire 2
#pragma unroll
        for (int i = 0; i < 16; i++)
            if (!(i & 2)) {
                const int j = i | 2;
                float r0 = re[i], i0 = im[i], r1 = re[j], i1 = im[j];
                re[i] = 0.5f * (r0 - i0 + r1 + i1);
                im[i] = 0.5f * (r0 + i0 - r1 + i1);
                re[j] = 0.5f * (r0 + i0 + r1 - i1);
                im[j] = 0.5f * (i0 - r0 + r1 + i1);
            }
    }
    g_cnot<1, 8>(re, im);

    float e0 = 0.f, e1 = 0.f, e2 = 0.f, e3 = 0.f;
#pragma unroll
    for (int i = 0; i < 16; i++) {
        float p = re[i] * re[i] + im[i] * im[i];
        e0 += (i & 8) ? -p : p;
        e1 += (i & 4) ? -p : p;
        e2 += (i & 2) ? -p : p;
        e3 += (i & 1) ? -p : p;
    }
    qout[b * 4 + 0] = e0;
    qout[b * 4 + 1] = e1;
    qout[b * 4 + 2] = e2;
    qout[b * 4 + 3] = e3;

    float v0 = e0, v1 = e1, v2 = e2, v3 = e3;
    float q0 = e0 * e0, q1 = e1 * e1, q2 = e2 * e2, q3 = e3 * e3;
#pragma unroll
    for (int d = 32; d > 0; d >>= 1) {
        v0 += __shfl_down(v0, d); v1 += __shfl_down(v1, d);
        v2 += __shfl_down(v2, d); v3 += __shfl_down(v3, d);
        q0 += __shfl_down(q0, d); q1 += __shfl_down(q1, d);
        q2 += __shfl_down(q2, d); q3 += __shfl_down(q3, d);
    }
    if (t == 0) {
        float* p1 = part1 + blockIdx.x * 8;
        p1[0] = v0; p1[1] = v1; p1[2] = v2; p1[3] = v3;
        p1[4] = q0; p1[5] = q1; p1[6] = q2; p1[7] = q3;
    }
}

// =====================================================================
// K3: reduce part1 -> BN-q stats; bn(q) -> concat -> final linear -> f;
//     emit per-block partials for BN-f stats.  16 blocks x 256.
// =====================================================================
__global__ __launch_bounds__(256) void k_bnq_linear(
    const float* __restrict__ qout, const float* __restrict__ mlp,
    const float* __restrict__ part1,
    const float* __restrict__ g, const float* __restrict__ bb,
    const float* __restrict__ fw, const float* __restrict__ fb,
    float* __restrict__ f, float* __restrict__ part2)
{
    __shared__ float st[8];
    __shared__ float red[8][256];
    const int t = threadIdx.x;
    if (t < 64) {
        float s[8];
#pragma unroll
        for (int j = 0; j < 8; j++) s[j] = part1[t * 8 + j];
#pragma unroll
        for (int d = 32; d > 0; d >>= 1)
#pragma unroll
            for (int j = 0; j < 8; j++) s[j] += __shfl_down(s[j], d);
        if (t == 0) {
#pragma unroll
            for (int j = 0; j < 4; j++) {
                float mean = s[j] * (1.0f / 4096.0f);
                float var = fmaxf(s[4 + j] * (1.0f / 4096.0f) - mean * mean, 0.0f);
                st[j] = mean;
                st[4 + j] = 1.0f / sqrtf(var + 1e-5f);
            }
        }
    }
    __syncthreads();

    const int row = blockIdx.x * 256 + t;
    const float4 q = ((const float4*)qout)[row];
    float c[5];
    c[0] = mlp[row];
    c[1] = (q.x - st[0]) * st[4] * g[0] + bb[0];
    c[2] = (q.y - st[1]) * st[5] * g[1] + bb[1];
    c[3] = (q.z - st[2]) * st[6] * g[2] + bb[2];
    c[4] = (q.w - st[3]) * st[7] * g[3] + bb[3];
    float fv[4];
#pragma unroll
    for (int o = 0; o < 4; o++) {
        float s = fb[o];
#pragma unroll
        for (int j = 0; j < 5; j++) s += fw[o * 5 + j] * c[j];
        fv[o] = s;
    }
    ((float4*)f)[row] = make_float4(fv[0], fv[1], fv[2], fv[3]);

#pragma unroll
    for (int j = 0; j < 4; j++) {
        red[j][t] = fv[j];
        red[4 + j][t] = fv[j] * fv[j];
    }
    __syncthreads();
    for (int off = 128; off > 0; off >>= 1) {
        if (t < off) {
#pragma unroll
            for (int j = 0; j < 8; j++) red[j][t] += red[j][t + off];
        }
        __syncthreads();
    }
    if (t < 8) part2[blockIdx.x * 8 + t] = red[t][0];
}

// =====================================================================
// K4: reduce part2 -> BN-f stats; final batchnorm -> out. 16 blocks x 256.
// =====================================================================
__global__ __launch_bounds__(256) void k_bnf(
    const float* __restrict__ f, const float* __restrict__ part2,
    const float* __restrict__ g, const float* __restrict__ bb,
    float* __restrict__ out)
{
    __shared__ float sums[8][16];
    __shared__ float st[8];
    const int t = threadIdx.x;
    if (t < 128) sums[t >> 4][t & 15] = part2[(t & 15) * 8 + (t >> 4)];
    __syncthreads();
    if (t < 8) {
        float s = 0.f;
#pragma unroll
        for (int b2_ = 0; b2_ < 16; b2_++) s += sums[t][b2_];
        sums[t][0] = s;
    }
    __syncthreads();
    if (t < 4) {
        float mean = sums[t][0] * (1.0f / 4096.0f);
        float var = fmaxf(sums[4 + t][0] * (1.0f / 4096.0f) - mean * mean, 0.0f);
        st[t] = mean;
        st[4 + t] = 1.0f / sqrtf(var + 1e-5f);
    }
    __syncthreads();
    const int row = blockIdx.x * 256 + t;
    const float4 v = ((const float4*)f)[row];
    float4 o;
    o.x = (v.x - st[0]) * st[4] * g[0] + bb[0];
    o.y = (v.y - st[1]) * st[5] * g[1] + bb[1];
    o.z = (v.z - st[2]) * st[6] * g[2] + bb[2];
    o.w = (v.w - st[3]) * st[7] * g[3] + bb[3];
    ((float4*)out)[row] = o;
}

// K5: diagnostic — only launched if anchors fail
__global__ void k_diag(float* __restrict__ out, float payload)
{
    out[0] = payload;
}

// =====================================================================
extern "C" void kernel_launch(void* const* d_in, const int* in_sizes, int n_in,
                              void* d_out, int out_size, void* d_ws, size_t ws_size,
                              hipStream_t stream) {
    (void)in_sizes; (void)n_in; (void)out_size; (void)ws_size;
    const float* x    = (const float*)d_in[0];
    const float* c1w  = (const float*)d_in[1];
    const float* c1b  = (const float*)d_in[2];
    const float* c2w  = (const float*)d_in[3];
    const float* c2b  = (const float*)d_in[4];
    const float* w1   = (const float*)d_in[5];
    const float* b1   = (const float*)d_in[6];
    const float* w2   = (const float*)d_in[7];
    const float* b2   = (const float*)d_in[8];
    const float* w3   = (const float*)d_in[9];
    const float* b3   = (const float*)d_in[10];
    const float* rl   = (const float*)d_in[11];
    const float* rx0  = (const float*)d_in[12];
    const float* ry0  = (const float*)d_in[13];
    const float* rz0  = (const float*)d_in[14];
    const float* crx0 = (const float*)d_in[15];
    const float* bqg  = (const float*)d_in[16];
    const float* bqb  = (const float*)d_in[17];
    const float* fw   = (const float*)d_in[18];
    const float* fb   = (const float*)d_in[19];
    const float* bfg  = (const float*)d_in[20];
    const float* bfb  = (const float*)d_in[21];

    float* ws = (float*)d_ws;
    float* pooled = ws;            // 4096*16
    float* mlp    = ws + 65536;    // 4096
    float* qout   = ws + 69632;    // 4096*4
    float* f      = ws + 86016;    // 4096*4
    float* part1  = ws + 102400;   // 64*8
    float* part2  = ws + 102912;   // 16*8

    OpsArg ops;
    gen_ops(ops);
    int am = anchors_mask();

    k_cnn<<<4096, 256, 0, stream>>>(x, c1w, c1b, c2w, c2b, w1, b1, w2, b2, w3, b3,
                                    pooled, mlp);
    k_quantum<<<64, 64, 0, stream>>>(pooled, rl, rx0, ry0, rz0, crx0, qout, part1, ops);
    k_bnq_linear<<<16, 256, 0, stream>>>(qout, mlp, part1, bqg, bqb, fw, fb, f, part2);
    k_bnf<<<16, 256, 0, stream>>>(f, part2, bfg, bfb, (float*)d_out);
    if (am != 7) {
        k_diag<<<1, 1, 0, stream>>>((float*)d_out, diag_payload(am));
    }
}

// Round 11
// 142.908 us; speedup vs baseline: 6.1038x; 6.1038x over previous
//
#include <hip/hip_runtime.h>
#include <stdint.h>

// =====================================================================
// Host-side RNG (HW-VERIFIED r7) — DO NOT TOUCH.
// =====================================================================
namespace rng42 {
typedef unsigned __int128 u128;

static inline uint32_t hashmix(uint32_t v, uint32_t& hc) {
    v ^= hc;
    hc *= 0x931e8875u;
    v *= hc;
    v ^= v >> 16;
    return v;
}
static inline uint32_t mixf(uint32_t x, uint32_t y) {
    uint32_t r = x * 0xca01f9ddu - y * 0x4973f715u;
    r ^= r >> 16;
    return r;
}

struct PCG64 {
    u128 state, inc;
    bool has32; uint32_t buf32;
    static inline u128 mult() {
        return ((u128)2549297995355413924ULL << 64) | (u128)4865540595714422341ULL;
    }
    inline void step() { state = state * mult() + inc; }
    void seed42() {
        uint32_t pool[4];
        uint32_t hc = 0x43b0d7e5u;
        pool[0] = hashmix(42u, hc);
        for (int i = 1; i < 4; i++) pool[i] = hashmix(0u, hc);
        for (int s = 0; s < 4; s++)
            for (int d = 0; d < 4; d++)
                if (s != d) pool[d] = mixf(pool[d], hashmix(pool[s], hc));
        uint32_t hb = 0x8b51f9ddu;
        uint32_t st32[8];
        for (int i = 0; i < 8; i++) {
            uint32_t dv = pool[i & 3];
            dv ^= hb;
            hb *= 0x58f38dedu;
            dv *= hb;
            dv ^= dv >> 16;
            st32[i] = dv;
        }
        uint64_t w0 = (uint64_t)st32[0] | ((uint64_t)st32[1] << 32);
        uint64_t w1 = (uint64_t)st32[2] | ((uint64_t)st32[3] << 32);
        uint64_t w2 = (uint64_t)st32[4] | ((uint64_t)st32[5] << 32);
        uint64_t w3 = (uint64_t)st32[6] | ((uint64_t)st32[7] << 32);
        u128 initstate = ((u128)w0 << 64) | (u128)w1;
        u128 initseq   = ((u128)w2 << 64) | (u128)w3;
        state = 0;
        inc = (initseq << 1) | 1;
        step();
        state += initstate;
        step();
        has32 = false; buf32 = 0;
    }
    uint64_t next64() {
        step();
        uint64_t lo = (uint64_t)state, hi = (uint64_t)(state >> 64);
        uint64_t x = hi ^ lo;
        unsigned rot = (unsigned)(uint64_t)(state >> 122);
        return (x >> rot) | (x << ((64u - rot) & 63u));
    }
    uint32_t next32() {
        if (has32) { has32 = false; return buf32; }
        uint64_t n = next64();
        has32 = true;
        buf32 = (uint32_t)(n >> 32);
        return (uint32_t)(n & 0xffffffffu);
    }
    uint32_t lemire32(uint32_t rng) {
        const uint32_t rng_excl = rng + 1u;
        uint64_t m = (uint64_t)next32() * (uint64_t)rng_excl;
        uint32_t leftover = (uint32_t)m;
        if (leftover < rng_excl) {
            const uint32_t threshold = (uint32_t)(0xFFFFFFFFu - rng) % rng_excl;
            while (leftover < threshold) {
                m = (uint64_t)next32() * (uint64_t)rng_excl;
                leftover = (uint32_t)m;
            }
        }
        return (uint32_t)(m >> 32);
    }
    uint32_t interval(uint32_t mx) {
        if (mx == 0) return 0;
        uint32_t mask = mx;
        mask |= mask >> 1; mask |= mask >> 2; mask |= mask >> 4;
        mask |= mask >> 8; mask |= mask >> 16;
        uint32_t value;
        while ((value = (next32() & mask)) > mx) {}
        return value;
    }
};
} // namespace rng42

struct OpsArg { int v[50]; };

static void gen_ops(OpsArg& o) {
    rng42::PCG64 g;
    g.seed42();
    for (int k = 0; k < 50; k++) {
        int t = (int)g.lemire32(3);
        if (t == 3) {
            int arr[4] = {0, 1, 2, 3};
            for (int i = 3; i >= 1; i--) {
                int j = (int)g.interval((uint32_t)i);
                if (i != j) { int tmp = arr[i]; arr[i] = arr[j]; arr[j] = tmp; }
            }
            o.v[k] = 3 | (arr[0] << 2) | (arr[1] << 4);
        } else {
            int w = (int)g.lemire32(3);
            o.v[k] = t | (w << 2);
        }
    }
}

static int anchors_mask() {
    rng42::PCG64 g;
    g.seed42();
    uint32_t c[6];
    for (int i = 0; i < 6; i++) c[i] = g.next32();
    int m = 0;
    if (c[1] >= 3324113900u && c[1] <= 3324117900u) m |= 1;
    if (c[3] >= 1884966500u && c[3] <= 1884970500u) m |= 2;
    if (c[5] >= 3687648000u && c[5] <= 3687652000u) m |= 4;
    return m;
}

static float diag_payload(int mask) {
    rng42::PCG64 g;
    g.seed42();
    uint64_t D = 0;
    for (int k = 0; k < 5; k++) {
        uint32_t c = g.next32();
        D = D * 10ull + (uint32_t)(((uint64_t)c * 10ull) >> 32);
    }
    return (float)((double)(2 + mask) * 1e7 + (double)D * 10.0);
}

// =====================================================================
// Quantum gate primitives (verified r7). State idx = q0*8+q1*4+q2*2+q3.
// =====================================================================
template<int MASK>
__device__ inline void g_rx(float c, float s, float* re, float* im) {
#pragma unroll
    for (int i = 0; i < 16; i++)
        if (!(i & MASK)) {
            const int j = i | MASK;
            float r0 = re[i], i0 = im[i], r1 = re[j], i1 = im[j];
            re[i] = c * r0 + s * i1; im[i] = c * i0 - s * r1;
            re[j] = s * i0 + c * r1; im[j] = c * i1 - s * r0;
        }
}
template<int MASK>
__device__ inline void g_ry(float c, float s, float* re, float* im) {
#pragma unroll
    for (int i = 0; i < 16; i++)
        if (!(i & MASK)) {
            const int j = i | MASK;
            float r0 = re[i], i0 = im[i], r1 = re[j], i1 = im[j];
            re[i] = c * r0 - s * r1; im[i] = c * i0 - s * i1;
            re[j] = s * r0 + c * r1; im[j] = s * i0 + c * i1;
        }
}
template<int MASK>
__device__ inline void g_rz(float c, float s, float* re, float* im) {
#pragma unroll
    for (int i = 0; i < 16; i++)
        if (!(i & MASK)) {
            const int j = i | MASK;
            float r0 = re[i], i0 = im[i], r1 = re[j], i1 = im[j];
            re[i] = c * r0 + s * i0; im[i] = c * i0 - s * r0;
            re[j] = c * r1 - s * i1; im[j] = c * i1 + s * r1;
        }
}
template<int CM, int TM>
__device__ inline void g_cnot(float* re, float* im) {
#pragma unroll
    for (int i = 0; i < 16; i++)
        if ((i & CM) && !(i & TM)) {
            const int j = i | TM;
            float tr = re[i]; re[i] = re[j]; re[j] = tr;
            float ti = im[i]; im[i] = im[j]; im[j] = ti;
        }
}

__device__ inline void rot_rt(int ty, int w, float c, float s, float* re, float* im) {
    switch (ty * 4 + w) {
        case 0:  g_rx<8>(c, s, re, im); break;
        case 1:  g_rx<4>(c, s, re, im); break;
        case 2:  g_rx<2>(c, s, re, im); break;
        case 3:  g_rx<1>(c, s, re, im); break;
        case 4:  g_ry<8>(c, s, re, im); break;
        case 5:  g_ry<4>(c, s, re, im); break;
        case 6:  g_ry<2>(c, s, re, im); break;
        case 7:  g_ry<1>(c, s, re, im); break;
        case 8:  g_rz<8>(c, s, re, im); break;
        case 9:  g_rz<4>(c, s, re, im); break;
        case 10: g_rz<2>(c, s, re, im); break;
        case 11: g_rz<1>(c, s, re, im); break;
        default: break;
    }
}
__device__ inline void cnot_rt(int w0, int w1, float* re, float* im) {
    switch (w0 * 4 + w1) {
        case 1:  g_cnot<8, 4>(re, im); break;
        case 2:  g_cnot<8, 2>(re, im); break;
        case 3:  g_cnot<8, 1>(re, im); break;
        case 4:  g_cnot<4, 8>(re, im); break;
        case 6:  g_cnot<4, 2>(re, im); break;
        case 7:  g_cnot<4, 1>(re, im); break;
        case 8:  g_cnot<2, 8>(re, im); break;
        case 9:  g_cnot<2, 4>(re, im); break;
        case 11: g_cnot<2, 1>(re, im); break;
        case 12: g_cnot<1, 8>(re, im); break;
        case 13: g_cnot<1, 4>(re, im); break;
        case 14: g_cnot<1, 2>(re, im); break;
        default: break;
    }
}

// swizzled channel-last site index for c1 (14x14): row pad + col skew
__device__ inline int c1site(int y, int x) { return y * 15 + x + (x >> 2); }

__device__ inline float dot4(const float4& w, const float4& p) {
    return w.x * p.x + w.y * p.y + w.z * p.z + w.w * p.w;
}

// =====================================================================
// K1: per-image CNN (r9 structure — known good).
// __launch_bounds__(256) only: let the allocator take ~96-128 VGPR for
// conv2's W[9] float4 block instead of spilling to scratch (r9/r10 bug:
// the (256,4) occupancy target squeezed VGPR to 64 and spilled).
// =====================================================================
__global__ __launch_bounds__(256) void k_cnn(
    const float* __restrict__ x,
    const float* __restrict__ c1w, const float* __restrict__ c1b,
    const float* __restrict__ c2w, const float* __restrict__ c2b,
    const float* __restrict__ w1, const float* __restrict__ b1,
    const float* __restrict__ w2, const float* __restrict__ b2,
    const float* __restrict__ w3, const float* __restrict__ b3,
    float* __restrict__ pooled_g, float* __restrict__ mlp_g)
{
    __shared__ __align__(16) float xs[784];
    __shared__ __align__(16) float c1s[216 * 8];
    __shared__ __align__(16) float c2s[784];
    __shared__ __align__(16) float cw1[72], cb1[8], wl2[1152], cb2[16];
    __shared__ float h1s[8];

    const int b = blockIdx.x;
    const int t = threadIdx.x;
    const float* xb = x + b * 784;
    for (int i = t; i < 784; i += 256) xs[i] = xb[i];
    if (t < 72) cw1[t] = c1w[t];
    if (t < 8) cb1[t] = c1b[t];
    // permute c2w [16][8][3][3] -> wl2 [16][3][3][8] (channel-last)
    for (int i = t; i < 1152; i += 256) {
        int oc = i / 72, r = i % 72, ic = r / 9, k9 = r % 9;
        wl2[(oc * 9 + k9) * 8 + ic] = c2w[i];
    }
    if (t < 16) cb2[t] = c2b[t];
    __syncthreads();

    // avg-pool 6x6 stride 6 -> pooled[16]
    if (t < 16) {
        int r0 = (t >> 2) * 6, c0 = (t & 3) * 6;
        float s = 0.f;
#pragma unroll
        for (int dy = 0; dy < 6; dy++)
#pragma unroll
            for (int dx = 0; dx < 6; dx++)
                s += xs[(r0 + dy) * 28 + (c0 + dx)];
        pooled_g[b * 16 + t] = s * (1.0f / 36.0f);
    }

    // conv1 + relu + 2x2 maxpool: 196 threads x 8 oc, channel-last out
    if (t < 196) {
        const int py = t / 14, px = t % 14;
        const int y0 = 2 * py - 1, x0 = 2 * px - 1;
        float patch[16];
#pragma unroll
        for (int i = 0; i < 4; i++)
#pragma unroll
            for (int j = 0; j < 4; j++) {
                int yy = y0 + i, xx = x0 + j;
                patch[i * 4 + j] = (yy >= 0 && yy < 28 && xx >= 0 && xx < 28)
                                       ? xs[yy * 28 + xx] : 0.f;
            }
        float m8[8];
#pragma unroll
        for (int oc = 0; oc < 8; oc++) {
            float w[9];
#pragma unroll
            for (int i = 0; i < 9; i++) w[i] = cw1[oc * 9 + i];
            float m = 0.f;
#pragma unroll
            for (int dy = 0; dy < 2; dy++)
#pragma unroll
                for (int dx = 0; dx < 2; dx++) {
                    float acc = cb1[oc];
#pragma unroll
                    for (int ky = 0; ky < 3; ky++)
#pragma unroll
                        for (int kx = 0; kx < 3; kx++)
                            acc += w[ky * 3 + kx] * patch[(dy + ky) * 4 + (dx + kx)];
                    m = fmaxf(m, acc);
                }
            m8[oc] = m;
        }
        float4* cv = (float4*)&c1s[c1site(py, px) * 8];
        cv[0] = make_float4(m8[0], m8[1], m8[2], m8[3]);
        cv[1] = make_float4(m8[4], m8[5], m8[6], m8[7]);
    }
    __syncthreads();

    // conv2 + relu + 2x2 maxpool: thread = (oc = t&15, pbase = t>>4);
    // pooled outputs p = pbase + 16*pi, pi = 0..3 (p < 49).
    {
        const int oc = t & 15;
        const int pbase = t >> 4;
        const float bias = cb2[oc];
        float a[4][2][2];
#pragma unroll
        for (int pi = 0; pi < 4; pi++)
#pragma unroll
            for (int dy = 0; dy < 2; dy++)
#pragma unroll
                for (int dx = 0; dx < 2; dx++) a[pi][dy][dx] = bias;

        const float4* wv = (const float4*)wl2;
        const float4* cv = (const float4*)c1s;
        const float4 z4 = make_float4(0.f, 0.f, 0.f, 0.f);

#pragma unroll
        for (int h = 0; h < 2; h++) {
            float4 W[9];
#pragma unroll
            for (int k = 0; k < 9; k++) W[k] = wv[(oc * 9 + k) * 2 + h];
#pragma unroll
            for (int pi = 0; pi < 4; pi++) {
                const int p = pbase + 16 * pi;
                if (p < 49) {
                    const int py = p / 7, px = p % 7;
                    const int y0 = 2 * py - 1, x0 = 2 * px - 1;
#pragma unroll
                    for (int i = 0; i < 4; i++) {
                        const int y = y0 + i;
                        float4 r[4];
                        if (y >= 0 && y < 14) {
#pragma unroll
                            for (int j = 0; j < 4; j++) {
                                const int xc = x0 + j;
                                r[j] = (xc >= 0 && xc < 14)
                                           ? cv[c1site(y, xc) * 2 + h] : z4;
                            }
                        } else {
#pragma unroll
                            for (int j = 0; j < 4; j++) r[j] = z4;
                        }
#pragma unroll
                        for (int dy = 0; dy < 2; dy++) {
                            if (dy <= i && i <= dy + 2) {  // static under unroll
                                const int ky = i - dy;
                                const float4 wk0 = W[ky * 3 + 0];
                                const float4 wk1 = W[ky * 3 + 1];
                                const float4 wk2 = W[ky * 3 + 2];
                                a[pi][dy][0] += dot4(wk0, r[0]) + dot4(wk1, r[1]) + dot4(wk2, r[2]);
                                a[pi][dy][1] += dot4(wk0, r[1]) + dot4(wk1, r[2]) + dot4(wk2, r[3]);
                            }
                        }
                    }
                }
            }
        }
#pragma unroll
        for (int pi = 0; pi < 4; pi++) {
            const int p = pbase + 16 * pi;
            if (p < 49) {
                float m = fmaxf(fmaxf(a[pi][0][0], a[pi][0][1]),
                                fmaxf(a[pi][1][0], a[pi][1][1]));
                c2s[oc * 49 + p] = fmaxf(m, 0.f);
            }
        }
    }
    __syncthreads();

    // MLP layer1: 8 outputs x 32 lanes each
    {
        int o = t >> 5, lane = t & 31;
        float s = 0.f;
        const float* wrow = w1 + o * 784;
        for (int k = lane; k < 784; k += 32) s += c2s[k] * wrow[k];
#pragma unroll
        for (int d = 16; d > 0; d >>= 1) s += __shfl_down(s, d, 32);
        if (lane == 0) h1s[o] = tanhf(s + b1[o]);
    }
    __syncthreads();
    if (t == 0) {
        float h2[4];
#pragma unroll
        for (int o = 0; o < 4; o++) {
            float s = b2[o];
#pragma unroll
            for (int j = 0; j < 8; j++) s += h1s[j] * w2[o * 8 + j];
            h2[o] = tanhf(s);
        }
        float s = b3[0];
#pragma unroll
        for (int j = 0; j < 4; j++) s += h2[j] * w3[j];
        mlp_g[b] = s;
    }
}

// =====================================================================
// K2: quantum block, one thread per batch element; block = 1 wave (64).
// Emits per-block partial sums/sumsq of qout for fused BN stats.
// =====================================================================
__global__ __launch_bounds__(64) void k_quantum(
    const float* __restrict__ pooled_g, const float* __restrict__ rl,
    const float* __restrict__ prx0, const float* __restrict__ pry0,
    const float* __restrict__ prz0, const float* __restrict__ pcrx0,
    float* __restrict__ qout, float* __restrict__ part1, OpsArg ops)
{
    __shared__ float rc[50], rs[50];
    const int t = threadIdx.x;
    if (t < 50) {
        float a = 0.5f * rl[t];
        rc[t] = cosf(a);
        rs[t] = sinf(a);
    }
    __syncthreads();

    const int b = blockIdx.x * 64 + t;
    float re[16], im[16];
#pragma unroll
    for (int i = 0; i < 16; i++) { re[i] = 0.f; im[i] = 0.f; }
    re[0] = 1.f;

    const float4* pv = (const float4*)(pooled_g + b * 16);
    float pb[16];
    {
        float4 p0 = pv[0], p1 = pv[1], p2 = pv[2], p3 = pv[3];
        pb[0] = p0.x; pb[1] = p0.y; pb[2] = p0.z; pb[3] = p0.w;
        pb[4] = p1.x; pb[5] = p1.y; pb[6] = p1.z; pb[7] = p1.w;
        pb[8] = p2.x; pb[9] = p2.y; pb[10] = p2.z; pb[11] = p2.w;
        pb[12] = p3.x; pb[13] = p3.y; pb[14] = p3.z; pb[15] = p3.w;
    }
    {
        float c, s, a;
        a = 0.5f * pb[0];  c = cosf(a); s = sinf(a); g_ry<8>(c, s, re, im);
        a = 0.5f * pb[1];  c = cosf(a); s = sinf(a); g_ry<4>(c, s, re, im);
        a = 0.5f * pb[2];  c = cosf(a); s = sinf(a); g_ry<2>(c, s, re, im);
        a = 0.5f * pb[3];  c = cosf(a); s = sinf(a); g_ry<1>(c, s, re, im);
        a = 0.5f * pb[4];  c = cosf(a); s = sinf(a); g_rz<8>(c, s, re, im);
        a = 0.5f * pb[5];  c = cosf(a); s = sinf(a); g_rz<4>(c, s, re, im);
        a = 0.5f * pb[6];  c = cosf(a); s = sinf(a); g_rz<2>(c, s, re, im);
        a = 0.5f * pb[7];  c = cosf(a); s = sinf(a); g_rz<1>(c, s, re, im);
        a = 0.5f * pb[8];  c = cosf(a); s = sinf(a); g_rx<8>(c, s, re, im);
        a = 0.5f * pb[9];  c = cosf(a); s = sinf(a); g_rx<4>(c, s, re, im);
        a = 0.5f * pb[10]; c = cosf(a); s = sinf(a); g_rx<2>(c, s, re, im);
        a = 0.5f * pb[11]; c = cosf(a); s = sinf(a); g_rx<1>(c, s, re, im);
        a = 0.5f * pb[12]; c = cosf(a); s = sinf(a); g_ry<8>(c, s, re, im);
        a = 0.5f * pb[13]; c = cosf(a); s = sinf(a); g_ry<4>(c, s, re, im);
        a = 0.5f * pb[14]; c = cosf(a); s = sinf(a); g_ry<2>(c, s, re, im);
        a = 0.5f * pb[15]; c = cosf(a); s = sinf(a); g_ry<1>(c, s, re, im);
    }

#pragma unroll 1
    for (int k = 0; k < 50; k++) {
        int v = ops.v[k];
        int ty = v & 3;
        int w0 = (v >> 2) & 3;
        int w1 = (v >> 4) & 3;
        if (ty == 3) cnot_rt(w0, w1, re, im);
        else         rot_rt(ty, w0, rc[k], rs[k], re, im);
    }

    { float a = 0.5f * prx0[0];  g_rx<8>(cosf(a), sinf(a), re, im); }
    { float a = 0.5f * pry0[0];  g_ry<4>(cosf(a), sinf(a), re, im); }
    { float a = 0.5f * prz0[0];  g_rz<1>(cosf(a), sinf(a), re, im); }
    { // crx (control wire0=mask8, target wire2=mask2)
        float a = 0.5f * pcrx0[0];
        float c = cosf(a), s = sinf(a);
#pragma unroll
        for (int i = 0; i < 16; i++)
            if ((i & 8) && !(i & 2)) {
                const int j = i | 2;
                float r0 = re[i], i0 = im[i], r1 = re[j], i1 = im[j];
                re[i] = c * r0 + s * i1; im[i] = c * i0 - s * r1;
                re[j] = s * i0 + c * r1; im[j] = c * i1 - s * r0;
            }
    }
    { // H wire 3
        const float r2 = 0.70710678118654752f;
#pragma unroll
        for (int i = 0; i < 16; i++)
            if (!(i & 1)) {
                const int j = i | 1;
                float r0 = re[i], i0 = im[i], r1 = re[j], i1 = im[j];
                re[i] = (r0 + r1) * r2; im[i] = (i0 + i1) * r2;
                re[j] = (r0 - r1) * r2; im[j] = (i0 - i1) * r2;
            }
    }
    { // SX wire 2
#pragma unroll
        for (int i = 0; i < 16; i++)
            if (!(i & 2)) {
                const int j = i | 2;
                float r0 = re[i], i0 = im[i], r1 = re[j], i1 = im[j];
                re[i] = 0.5f * (r0 - i0 + r1 + i1);
                im[i] = 0.5f * (r0 + i0 - r1 + i1);
                re[j] = 0.5f * (r0 + i0 + r1 - i1);
                im[j] = 0.5f * (i0 - r0 + r1 + i1);
            }
    }
    g_cnot<1, 8>(re, im);

    float e0 = 0.f, e1 = 0.f, e2 = 0.f, e3 = 0.f;
#pragma unroll
    for (int i = 0; i < 16; i++) {
        float p = re[i] * re[i] + im[i] * im[i];
        e0 += (i & 8) ? -p : p;
        e1 += (i & 4) ? -p : p;
        e2 += (i & 2) ? -p : p;
        e3 += (i & 1) ? -p : p;
    }
    qout[b * 4 + 0] = e0;
    qout[b * 4 + 1] = e1;
    qout[b * 4 + 2] = e2;
    qout[b * 4 + 3] = e3;

    float v0 = e0, v1 = e1, v2 = e2, v3 = e3;
    float q0 = e0 * e0, q1 = e1 * e1, q2 = e2 * e2, q3 = e3 * e3;
#pragma unroll
    for (int d = 32; d > 0; d >>= 1) {
        v0 += __shfl_down(v0, d); v1 += __shfl_down(v1, d);
        v2 += __shfl_down(v2, d); v3 += __shfl_down(v3, d);
        q0 += __shfl_down(q0, d); q1 += __shfl_down(q1, d);
        q2 += __shfl_down(q2, d); q3 += __shfl_down(q3, d);
    }
    if (t == 0) {
        float* p1 = part1 + blockIdx.x * 8;
        p1[0] = v0; p1[1] = v1; p1[2] = v2; p1[3] = v3;
        p1[4] = q0; p1[5] = q1; p1[6] = q2; p1[7] = q3;
    }
}

// =====================================================================
// K3: reduce part1 -> BN-q stats; bn(q) -> concat -> final linear -> f;
//     emit per-block partials for BN-f stats.  16 blocks x 256.
// =====================================================================
__global__ __launch_bounds__(256) void k_bnq_linear(
    const float* __restrict__ qout, const float* __restrict__ mlp,
    const float* __restrict__ part1,
    const float* __restrict__ g, const float* __restrict__ bb,
    const float* __restrict__ fw, const float* __restrict__ fb,
    float* __restrict__ f, float* __restrict__ part2)
{
    __shared__ float st[8];
    __shared__ float red[8][256];
    const int t = threadIdx.x;
    if (t < 64) {
        float s[8];
#pragma unroll
        for (int j = 0; j < 8; j++) s[j] = part1[t * 8 + j];
#pragma unroll
        for (int d = 32; d > 0; d >>= 1)
#pragma unroll
            for (int j = 0; j < 8; j++) s[j] += __shfl_down(s[j], d);
        if (t == 0) {
#pragma unroll
            for (int j = 0; j < 4; j++) {
                float mean = s[j] * (1.0f / 4096.0f);
                float var = fmaxf(s[4 + j] * (1.0f / 4096.0f) - mean * mean, 0.0f);
                st[j] = mean;
                st[4 + j] = 1.0f / sqrtf(var + 1e-5f);
            }
        }
    }
    __syncthreads();

    const int row = blockIdx.x * 256 + t;
    const float4 q = ((const float4*)qout)[row];
    float c[5];
    c[0] = mlp[row];
    c[1] = (q.x - st[0]) * st[4] * g[0] + bb[0];
    c[2] = (q.y - st[1]) * st[5] * g[1] + bb[1];
    c[3] = (q.z - st[2]) * st[6] * g[2] + bb[2];
    c[4] = (q.w - st[3]) * st[7] * g[3] + bb[3];
    float fv[4];
#pragma unroll
    for (int o = 0; o < 4; o++) {
        float s = fb[o];
#pragma unroll
        for (int j = 0; j < 5; j++) s += fw[o * 5 + j] * c[j];
        fv[o] = s;
    }
    ((float4*)f)[row] = make_float4(fv[0], fv[1], fv[2], fv[3]);

#pragma unroll
    for (int j = 0; j < 4; j++) {
        red[j][t] = fv[j];
        red[4 + j][t] = fv[j] * fv[j];
    }
    __syncthreads();
    for (int off = 128; off > 0; off >>= 1) {
        if (t < off) {
#pragma unroll
            for (int j = 0; j < 8; j++) red[j][t] += red[j][t + off];
        }
        __syncthreads();
    }
    if (t < 8) part2[blockIdx.x * 8 + t] = red[t][0];
}

// =====================================================================
// K4: reduce part2 -> BN-f stats; final batchnorm -> out. 16 blocks x 256.
// =====================================================================
__global__ __launch_bounds__(256) void k_bnf(
    const float* __restrict__ f, const float* __restrict__ part2,
    const float* __restrict__ g, const float* __restrict__ bb,
    float* __restrict__ out)
{
    __shared__ float sums[8][16];
    __shared__ float st[8];
    const int t = threadIdx.x;
    if (t < 128) sums[t >> 4][t & 15] = part2[(t & 15) * 8 + (t >> 4)];
    __syncthreads();
    if (t < 8) {
        float s = 0.f;
#pragma unroll
        for (int b2_ = 0; b2_ < 16; b2_++) s += sums[t][b2_];
        sums[t][0] = s;
    }
    __syncthreads();
    if (t < 4) {
        float mean = sums[t][0] * (1.0f / 4096.0f);
        float var = fmaxf(sums[4 + t][0] * (1.0f / 4096.0f) - mean * mean, 0.0f);
        st[t] = mean;
        st[4 + t] = 1.0f / sqrtf(var + 1e-5f);
    }
    __syncthreads();
    const int row = blockIdx.x * 256 + t;
    const float4 v = ((const float4*)f)[row];
    float4 o;
    o.x = (v.x - st[0]) * st[4] * g[0] + bb[0];
    o.y = (v.y - st[1]) * st[5] * g[1] + bb[1];
    o.z = (v.z - st[2]) * st[6] * g[2] + bb[2];
    o.w = (v.w - st[3]) * st[7] * g[3] + bb[3];
    ((float4*)out)[row] = o;
}

// K5: diagnostic — only launched if anchors fail
__global__ void k_diag(float* __restrict__ out, float payload)
{
    out[0] = payload;
}

// =====================================================================
extern "C" void kernel_launch(void* const* d_in, const int* in_sizes, int n_in,
                              void* d_out, int out_size, void* d_ws, size_t ws_size,
                              hipStream_t stream) {
    (void)in_sizes; (void)n_in; (void)out_size; (void)ws_size;
    const float* x    = (const float*)d_in[0];
    const float* c1w  = (const float*)d_in[1];
    const float* c1b  = (const float*)d_in[2];
    const float* c2w  = (const float*)d_in[3];
    const float* c2b  = (const float*)d_in[4];
    const float* w1   = (const float*)d_in[5];
    const float* b1   = (const float*)d_in[6];
    const float* w2   = (const float*)d_in[7];
    const float* b2   = (const float*)d_in[8];
    const float* w3   = (const float*)d_in[9];
    const float* b3   = (const float*)d_in[10];
    const float* rl   = (const float*)d_in[11];
    const float* rx0  = (const float*)d_in[12];
    const float* ry0  = (const float*)d_in[13];
    const float* rz0  = (const float*)d_in[14];
    const float* crx0 = (const float*)d_in[15];
    const float* bqg  = (const float*)d_in[16];
    const float* bqb  = (const float*)d_in[17];
    const float* fw   = (const float*)d_in[18];
    const float* fb   = (const float*)d_in[19];
    const float* bfg  = (const float*)d_in[20];
    const float* bfb  = (const float*)d_in[21];

    float* ws = (float*)d_ws;
    float* pooled = ws;            // 4096*16
    float* mlp    = ws + 65536;    // 4096
    float* qout   = ws + 69632;    // 4096*4
    float* f      = ws + 86016;    // 4096*4
    float* part1  = ws + 102400;   // 64*8
    float* part2  = ws + 102912;   // 16*8

    OpsArg ops;
    gen_ops(ops);
    int am = anchors_mask();

    k_cnn<<<4096, 256, 0, stream>>>(x, c1w, c1b, c2w, c2b, w1, b1, w2, b2, w3, b3,
                                    pooled, mlp);
    k_quantum<<<64, 64, 0, stream>>>(pooled, rl, rx0, ry0, rz0, crx0, qout, part1, ops);
    k_bnq_linear<<<16, 256, 0, stream>>>(qout, mlp, part1, bqg, bqb, fw, fb, f, part2);
    k_bnf<<<16, 256, 0, stream>>>(f, part2, bfg, bfb, (float*)d_out);
    if (am != 7) {
        k_diag<<<1, 1, 0, stream>>>((float*)d_out, diag_payload(am));
    }
}